// Round 2
// baseline (877.830 us; speedup 1.0000x reference)
//
#include <hip/hip_runtime.h>

#define D 128

// ---------- graph preprocessing ----------
// NOTE: harness delivers integer inputs as int32 (edge_index arrives as int*).

__global__ void k_count(const int* __restrict__ ei, int* __restrict__ cnt, int E) {
    int e = blockIdx.x * 256 + threadIdx.x;
    if (e < E) atomicAdd(&cnt[ei[E + e]], 1);
}

__global__ void k_chunksum(const int* __restrict__ cnt, int* __restrict__ chunk, int N) {
    __shared__ int sh[256];
    int t = threadIdx.x;
    int i0 = blockIdx.x * 1024 + t * 4;
    int s = 0;
#pragma unroll
    for (int j = 0; j < 4; j++) { int i = i0 + j; if (i < N) s += cnt[i]; }
    sh[t] = s; __syncthreads();
    for (int d = 128; d > 0; d >>= 1) {
        if (t < d) sh[t] += sh[t + d];
        __syncthreads();
    }
    if (t == 0) chunk[blockIdx.x] = sh[0];
}

__global__ void k_scanchunks(int* __restrict__ chunk, int* __restrict__ row_ptr, int nchunk, int N) {
    if (threadIdx.x == 0 && blockIdx.x == 0) {
        int run = 0;
        for (int c = 0; c < nchunk; c++) { int v = chunk[c]; chunk[c] = run; run += v; }
        row_ptr[N] = run;   // == E
    }
}

__global__ void k_rowptr(const int* __restrict__ cnt, const int* __restrict__ chunk,
                         int* __restrict__ row_ptr, int* __restrict__ cursor,
                         float* __restrict__ dis, int N) {
    __shared__ int sh[256];
    int t = threadIdx.x;
    int i0 = blockIdx.x * 1024 + t * 4;
    int v[4]; int s = 0;
#pragma unroll
    for (int j = 0; j < 4; j++) { int i = i0 + j; v[j] = (i < N) ? cnt[i] : 0; s += v[j]; }
    sh[t] = s; __syncthreads();
    // Hillis-Steele inclusive scan over thread sums
    for (int d = 1; d < 256; d <<= 1) {
        int xv = (t >= d) ? sh[t - d] : 0;
        __syncthreads();
        sh[t] += xv;
        __syncthreads();
    }
    int run = chunk[blockIdx.x] + sh[t] - s;  // exclusive prefix for this thread
#pragma unroll
    for (int j = 0; j < 4; j++) {
        int i = i0 + j;
        if (i < N) {
            row_ptr[i] = run; cursor[i] = run; run += v[j];
            dis[i] = rsqrtf((float)(v[j] + 1));   // +1 self loop
        }
    }
}

__global__ void k_fill(const int* __restrict__ ei, int* __restrict__ cursor,
                       int* __restrict__ col, int E) {
    int e = blockIdx.x * 256 + threadIdx.x;
    if (e < E) {
        int s = ei[e];
        int d = ei[E + e];
        int p = atomicAdd(&cursor[d], 1);
        col[p] = s;
    }
}

// ---------- dense: g = (in @ W^T) * dis ----------
// One row per lane. W indices are wave-uniform -> scalar loads (s_load),
// so every VALU inst is a full 64-lane FMA. x row lives in 128 VGPRs.

__global__ __launch_bounds__(256) void k_gemm(const float* __restrict__ in,
                                              const float* __restrict__ W,
                                              const float* __restrict__ dis,
                                              float* __restrict__ g, int N) {
    int row = blockIdx.x * 256 + threadIdx.x;
    int r = (row < N) ? row : (N - 1);
    float xr[D];
    const float4* xin = (const float4*)(in + (size_t)r * D);
#pragma unroll
    for (int q = 0; q < D / 4; q++) {
        float4 v = xin[q];
        xr[4 * q + 0] = v.x; xr[4 * q + 1] = v.y; xr[4 * q + 2] = v.z; xr[4 * q + 3] = v.w;
    }
    float dv = dis[r];
    float4* go = (float4*)(g + (size_t)r * D);
    for (int j = 0; j < D; j += 4) {
        float a0 = 0.f, a1 = 0.f, a2 = 0.f, a3 = 0.f;
        const float* w0 = W + (size_t)j * D;
#pragma unroll
        for (int k = 0; k < D; k++) {
            float xk = xr[k];
            a0 = fmaf(xk, w0[k], a0);
            a1 = fmaf(xk, w0[D + k], a1);
            a2 = fmaf(xk, w0[2 * D + k], a2);
            a3 = fmaf(xk, w0[3 * D + k], a3);
        }
        if (row < N) go[j / 4] = make_float4(a0 * dv, a1 * dv, a2 * dv, a3 * dv);
    }
}

// ---------- sparse aggregation ----------
// half-wave (32 lanes x float4 = 512B) per node:
// out[v] = dis[v]*(sum_{u in N(v)} g[u] + g[v]) + bias   (ReLU optional)

template <bool RELU>
__global__ __launch_bounds__(256) void k_agg(const float* __restrict__ g,
                                             const int* __restrict__ rp,
                                             const int* __restrict__ col,
                                             const float* __restrict__ dis,
                                             const float* __restrict__ bias,
                                             float* __restrict__ out, int N) {
    int node = blockIdx.x * 8 + (threadIdx.x >> 5);
    if (node >= N) return;
    int lane = threadIdx.x & 31;
    const float4* G = (const float4*)g;
    float4 acc = G[(size_t)node * 32 + lane];   // self-loop term g[v]
    int b = rp[node], e = rp[node + 1];
    int i = b;
    for (; i + 1 < e; i += 2) {
        int u0 = col[i], u1 = col[i + 1];
        float4 m0 = G[(size_t)u0 * 32 + lane];
        float4 m1 = G[(size_t)u1 * 32 + lane];
        acc.x += m0.x + m1.x; acc.y += m0.y + m1.y;
        acc.z += m0.z + m1.z; acc.w += m0.w + m1.w;
    }
    if (i < e) {
        int u = col[i];
        float4 m = G[(size_t)u * 32 + lane];
        acc.x += m.x; acc.y += m.y; acc.z += m.z; acc.w += m.w;
    }
    float s = dis[node];
    float4 bb = ((const float4*)bias)[lane];
    float4 r;
    r.x = fmaf(acc.x, s, bb.x);
    r.y = fmaf(acc.y, s, bb.y);
    r.z = fmaf(acc.z, s, bb.z);
    r.w = fmaf(acc.w, s, bb.w);
    if (RELU) {
        r.x = fmaxf(r.x, 0.f); r.y = fmaxf(r.y, 0.f);
        r.z = fmaxf(r.z, 0.f); r.w = fmaxf(r.w, 0.f);
    }
    ((float4*)out)[(size_t)node * 32 + lane] = r;
}

// ---------- launch ----------

extern "C" void kernel_launch(void* const* d_in, const int* in_sizes, int n_in,
                              void* d_out, int out_size, void* d_ws, size_t ws_size,
                              hipStream_t stream) {
    const float* x  = (const float*)d_in[0];
    const int*   ei = (const int*)d_in[1];
    const float* W1 = (const float*)d_in[2];
    const float* b1 = (const float*)d_in[3];
    const float* W2 = (const float*)d_in[4];
    const float* b2 = (const float*)d_in[5];
    float* out = (float*)d_out;

    int N = in_sizes[0] / D;
    int E = in_sizes[1] / 2;

    char* w = (char*)d_ws;
    float* g       = (float*)w;            size_t off = (size_t)N * D * 4;
    int*   cnt     = (int*)(w + off);      off += (size_t)N * 4;
    int*   row_ptr = (int*)(w + off);      off += (size_t)(N + 4) * 4;
    int*   cursor  = (int*)(w + off);      off += (size_t)N * 4;
    float* dis     = (float*)(w + off);    off += (size_t)N * 4;
    int*   chunk   = (int*)(w + off);      off += 4096;
    int*   col     = (int*)(w + off);      off += (size_t)E * 4;

    int nchunk = (N + 1023) / 1024;

    hipMemsetAsync(cnt, 0, (size_t)N * 4, stream);
    k_count<<<(E + 255) / 256, 256, 0, stream>>>(ei, cnt, E);
    k_chunksum<<<nchunk, 256, 0, stream>>>(cnt, chunk, N);
    k_scanchunks<<<1, 64, 0, stream>>>(chunk, row_ptr, nchunk, N);
    k_rowptr<<<nchunk, 256, 0, stream>>>(cnt, chunk, row_ptr, cursor, dis, N);
    k_fill<<<(E + 255) / 256, 256, 0, stream>>>(ei, cursor, col, E);

    // layer 1: g = (x @ W1^T)*dis ; out1 = relu(agg + b1)  -> d_out (scratch)
    k_gemm<<<(N + 255) / 256, 256, 0, stream>>>(x, W1, dis, g, N);
    k_agg<true><<<(N + 7) / 8, 256, 0, stream>>>(g, row_ptr, col, dis, b1, out, N);

    // layer 2: g2 = (out1 @ W2^T)*dis ; final = agg + b2 -> d_out
    k_gemm<<<(N + 255) / 256, 256, 0, stream>>>(out, W2, dis, g, N);
    k_agg<false><<<(N + 7) / 8, 256, 0, stream>>>(g, row_ptr, col, dis, b2, out, N);
}